// Round 1
// baseline (2262.255 us; speedup 1.0000x reference)
//
#include <hip/hip_runtime.h>
#include <math.h>

#define NN 100000      // nodes
#define NE 1600000     // edges
#define C  32          // channels (C_IN == C_OUT == 32)

// ---------------------------------------------------------------------------
// deg[src] += w   (segment_sum over src)
// ---------------------------------------------------------------------------
__global__ __launch_bounds__(256) void deg_kernel(const int* __restrict__ ei,
                                                  const float* __restrict__ w,
                                                  float* __restrict__ deg) {
    int e = blockIdx.x * blockDim.x + threadIdx.x;
    if (e < NE) atomicAdd(&deg[ei[e]], w[e]);
}

// ---------------------------------------------------------------------------
// coef[e] = -(dis[src] * w * dis[dst]),  dis = deg>0 ? rsqrt(deg) : 0
// ---------------------------------------------------------------------------
__global__ __launch_bounds__(256) void coef_kernel(const int* __restrict__ ei,
                                                   const float* __restrict__ w,
                                                   const float* __restrict__ deg,
                                                   float* __restrict__ coef) {
    int e = blockIdx.x * blockDim.x + threadIdx.x;
    if (e >= NE) return;
    int s = ei[e], d = ei[NE + e];
    float ds = deg[s], dd = deg[d];
    float is = ds > 0.f ? rsqrtf(ds) : 0.f;
    float id = dd > 0.f ? rsqrtf(dd) : 0.f;
    coef[e] = -(is * w[e] * id);
}

// ---------------------------------------------------------------------------
// agg_x[dst] += coef * x[src];  agg_h[dst] += coef * h[src]
// 8 threads per edge, 4 channels each (float4 gather, 4B fp32 atomics)
// ---------------------------------------------------------------------------
__global__ __launch_bounds__(256) void scatter_xh(const int* __restrict__ ei,
                                                  const float* __restrict__ coef,
                                                  const float* __restrict__ x,
                                                  const float* __restrict__ h,
                                                  float* __restrict__ agg_x,
                                                  float* __restrict__ agg_h) {
    int t = blockIdx.x * blockDim.x + threadIdx.x;   // t < NE*8
    int e = t >> 3;
    int c = (t & 7) << 2;
    int s = ei[e], d = ei[NE + e];
    float cf = coef[e];
    const float4 xv = *(const float4*)(x + (size_t)s * C + c);
    const float4 hv = *(const float4*)(h + (size_t)s * C + c);
    float* ax = agg_x + (size_t)d * C + c;
    float* ah = agg_h + (size_t)d * C + c;
    atomicAdd(ax + 0, cf * xv.x);
    atomicAdd(ax + 1, cf * xv.y);
    atomicAdd(ax + 2, cf * xv.z);
    atomicAdd(ax + 3, cf * xv.w);
    atomicAdd(ah + 0, cf * hv.x);
    atomicAdd(ah + 1, cf * hv.y);
    atomicAdd(ah + 2, cf * hv.z);
    atomicAdd(ah + 3, cf * hv.w);
}

// ---------------------------------------------------------------------------
// agg_hr[dst] += coef * hr[src]
// ---------------------------------------------------------------------------
__global__ __launch_bounds__(256) void scatter_hr(const int* __restrict__ ei,
                                                  const float* __restrict__ coef,
                                                  const float* __restrict__ hr,
                                                  float* __restrict__ agg_hr) {
    int t = blockIdx.x * blockDim.x + threadIdx.x;
    int e = t >> 3;
    int c = (t & 7) << 2;
    int s = ei[e], d = ei[NE + e];
    float cf = coef[e];
    const float4 v = *(const float4*)(hr + (size_t)s * C + c);
    float* a = agg_hr + (size_t)d * C + c;
    atomicAdd(a + 0, cf * v.x);
    atomicAdd(a + 1, cf * v.y);
    atomicAdd(a + 2, cf * v.z);
    atomicAdd(a + 3, cf * v.w);
}

// ---------------------------------------------------------------------------
// Per node: z = sigmoid(x@Wx00 + ax@Wx01 + h@Wh00 + ah@Wh01 + bz)
//           r = sigmoid(... g=1 ...)
//           hr = h * r
//           ph = x@Wx20 + ax@Wx21 + bx2 + bh2   (r-independent part of h~)
// Block = 256 threads = 8 nodes x 32 output channels.
// Weight matrices staged in LDS: 10 x (32x32).
//   m: 0=Wx[0,0] 1=Wx[0,1] 2=Wh[0,0] 3=Wh[0,1] 4=Wx[1,0] 5=Wx[1,1]
//      6=Wh[1,0] 7=Wh[1,1] 8=Wx[2,0] 9=Wx[2,1]
// ---------------------------------------------------------------------------
__global__ __launch_bounds__(256) void gate_zr(const float* __restrict__ x,
                                               const float* __restrict__ h,
                                               const float* __restrict__ agg_x,
                                               const float* __restrict__ agg_h,
                                               const float* __restrict__ Wx,
                                               const float* __restrict__ Wh,
                                               const float* __restrict__ bx,
                                               const float* __restrict__ bh,
                                               float* __restrict__ zout,
                                               float* __restrict__ hrout,
                                               float* __restrict__ pout) {
    __shared__ float sW[10 * 1024];
    __shared__ float sIn[4][8][C];
    int tid = threadIdx.x;
    for (int i = tid; i < 10 * 1024; i += 256) {
        int m = i >> 10, r = i & 1023;
        int g = m >> 2, pair = m & 3;
        const float* src = (pair & 2) ? Wh : Wx;
        sW[i] = src[g * 2048 + (pair & 1) * 1024 + r];
    }
    int nl = tid >> 5, j = tid & 31;
    int n = blockIdx.x * 8 + nl;
    sIn[0][nl][j] = x[n * C + j];
    sIn[1][nl][j] = agg_x[n * C + j];
    sIn[2][nl][j] = h[n * C + j];
    sIn[3][nl][j] = agg_h[n * C + j];
    __syncthreads();

    float accz = bx[j] + bh[j];
    float accr = bx[32 + j] + bh[32 + j];
    float accp = bx[64 + j] + bh[64 + j];
#pragma unroll
    for (int k = 0; k < C; ++k) {
        float xk = sIn[0][nl][k];
        float ak = sIn[1][nl][k];
        float hk = sIn[2][nl][k];
        float gk = sIn[3][nl][k];
        int o = k * 32 + j;
        accz = fmaf(xk, sW[o], accz);
        accz = fmaf(ak, sW[1024 + o], accz);
        accz = fmaf(hk, sW[2048 + o], accz);
        accz = fmaf(gk, sW[3072 + o], accz);
        accr = fmaf(xk, sW[4096 + o], accr);
        accr = fmaf(ak, sW[5120 + o], accr);
        accr = fmaf(hk, sW[6144 + o], accr);
        accr = fmaf(gk, sW[7168 + o], accr);
        accp = fmaf(xk, sW[8192 + o], accp);
        accp = fmaf(ak, sW[9216 + o], accp);
    }
    float z = 1.f / (1.f + expf(-accz));
    float r = 1.f / (1.f + expf(-accr));
    zout[n * C + j]  = z;
    hrout[n * C + j] = sIn[2][nl][j] * r;
    pout[n * C + j]  = accp;
}

// ---------------------------------------------------------------------------
// h~ = tanh(ph + hr@Wh[2,0] + agg_hr@Wh[2,1])
// h_new = z*h + (1-z)*h~
// out[n] = softplus(relu(h_new) . Wl + bl)
// ---------------------------------------------------------------------------
__global__ __launch_bounds__(256) void final_kernel(const float* __restrict__ h,
                                                    const float* __restrict__ z,
                                                    const float* __restrict__ hr,
                                                    const float* __restrict__ agg_hr,
                                                    const float* __restrict__ ph,
                                                    const float* __restrict__ Wh,
                                                    const float* __restrict__ Wl,
                                                    const float* __restrict__ bl,
                                                    float* __restrict__ out,
                                                    float* __restrict__ hnew) {
    __shared__ float sW[2 * 1024];
    __shared__ float sIn[2][8][C];
    int tid = threadIdx.x;
    for (int i = tid; i < 2 * 1024; i += 256) sW[i] = Wh[4096 + i]; // Wh[2,0], Wh[2,1]
    int nl = tid >> 5, j = tid & 31;
    int n = blockIdx.x * 8 + nl;
    sIn[0][nl][j] = hr[n * C + j];
    sIn[1][nl][j] = agg_hr[n * C + j];
    __syncthreads();

    float acc = ph[n * C + j];
#pragma unroll
    for (int k = 0; k < C; ++k) {
        int o = k * 32 + j;
        acc = fmaf(sIn[0][nl][k], sW[o], acc);
        acc = fmaf(sIn[1][nl][k], sW[1024 + o], acc);
    }
    float ht = tanhf(acc);
    float zv = z[n * C + j];
    float hv = h[n * C + j];
    float hn = fmaf(zv, hv - ht, ht);   // z*h + (1-z)*ht
    hnew[n * C + j] = hn;

    float p = fmaxf(hn, 0.f) * Wl[j];
#pragma unroll
    for (int off = 16; off; off >>= 1) p += __shfl_down(p, off, 32);
    if (j == 0) {
        float v = p + bl[0];
        out[n] = fmaxf(v, 0.f) + log1pf(expf(-fabsf(v)));   // stable softplus
    }
}

// ---------------------------------------------------------------------------
extern "C" void kernel_launch(void* const* d_in, const int* in_sizes, int n_in,
                              void* d_out, int out_size, void* d_ws, size_t ws_size,
                              hipStream_t stream) {
    const float* x  = (const float*)d_in[0];
    const int*   ei = (const int*)d_in[1];
    const float* ew = (const float*)d_in[2];
    const float* h  = (const float*)d_in[3];
    const float* Wx = (const float*)d_in[4];
    const float* bx = (const float*)d_in[5];
    const float* Wh = (const float*)d_in[6];
    const float* bh = (const float*)d_in[7];
    const float* Wl = (const float*)d_in[8];
    const float* bl = (const float*)d_in[9];

    float* out  = (float*)d_out;        // [N,1]
    float* hnew = out + NN;             // [N,32]

    float* ws     = (float*)d_ws;
    float* deg    = ws;                                  // 100352 (padded)
    float* agg_x  = ws + 100352;                         // N*C
    float* agg_h  = agg_x + (size_t)NN * C;              // N*C
    float* agg_hr = agg_h + (size_t)NN * C;              // N*C
    float* coef   = agg_hr + (size_t)NN * C;             // NE
    float* zbuf   = coef + NE;                           // N*C
    float* hrbuf  = zbuf + (size_t)NN * C;               // N*C
    float* pbuf   = hrbuf + (size_t)NN * C;              // N*C

    // zero deg + agg_x + agg_h + agg_hr in one shot (contiguous)
    size_t zero_bytes = (size_t)(100352 + 3 * (size_t)NN * C) * sizeof(float);
    hipMemsetAsync(d_ws, 0, zero_bytes, stream);

    deg_kernel <<<(NE + 255) / 256, 256, 0, stream>>>(ei, ew, deg);
    coef_kernel<<<(NE + 255) / 256, 256, 0, stream>>>(ei, ew, deg, coef);
    scatter_xh <<<(NE * 8) / 256, 256, 0, stream>>>(ei, coef, x, h, agg_x, agg_h);
    gate_zr    <<<NN / 8, 256, 0, stream>>>(x, h, agg_x, agg_h, Wx, Wh, bx, bh,
                                            zbuf, hrbuf, pbuf);
    scatter_hr <<<(NE * 8) / 256, 256, 0, stream>>>(ei, coef, hrbuf, agg_hr);
    final_kernel<<<NN / 8, 256, 0, stream>>>(h, zbuf, hrbuf, agg_hr, pbuf,
                                             Wh, Wl, bl, out, hnew);
}

// Round 2
// 601.493 us; speedup vs baseline: 3.7611x; 3.7611x over previous
//
#include <hip/hip_runtime.h>
#include <math.h>

#define NN 100000      // nodes
#define NE 1600000     // edges
#define C  32          // channels
#define NP 100352      // NN padded to 98*1024

// ---------------------------------------------------------------------------
// deg[src] += w (fp32) ; cnt[dst] += 1 (int histogram for counting sort)
// ---------------------------------------------------------------------------
__global__ __launch_bounds__(256) void deg_hist(const int* __restrict__ ei,
                                                const float* __restrict__ w,
                                                float* __restrict__ deg,
                                                int* __restrict__ cnt) {
    int e = blockIdx.x * blockDim.x + threadIdx.x;
    if (e >= NE) return;
    atomicAdd(&deg[ei[e]], w[e]);
    atomicAdd(&cnt[ei[NE + e]], 1);
}

// ---------------------------------------------------------------------------
// scan1: per-block (1024-wide) exclusive scan of cnt -> pref, block totals
// ---------------------------------------------------------------------------
__global__ __launch_bounds__(1024) void scan1(const int* __restrict__ cnt,
                                              int* __restrict__ pref,
                                              int* __restrict__ bsum) {
    int i = blockIdx.x * 1024 + threadIdx.x;
    int v = cnt[i];
    int lane = threadIdx.x & 63, wid = threadIdx.x >> 6;  // 16 waves of 64
    int inc = v;
#pragma unroll
    for (int off = 1; off < 64; off <<= 1) {
        int t = __shfl_up(inc, off, 64);
        if (lane >= off) inc += t;
    }
    __shared__ int ws[16];
    if (lane == 63) ws[wid] = inc;
    __syncthreads();
    if (wid == 0) {
        int s = (lane < 16) ? ws[lane] : 0;
#pragma unroll
        for (int off = 1; off < 16; off <<= 1) {
            int t = __shfl_up(s, off, 64);
            if (lane >= off) s += t;
        }
        if (lane < 16) ws[lane] = s;
    }
    __syncthreads();
    int wbase = wid ? ws[wid - 1] : 0;
    pref[i] = wbase + inc - v;                  // exclusive within block
    if (threadIdx.x == 1023) bsum[blockIdx.x] = wbase + inc;
}

// scan2: exclusive scan of 98 block totals (tiny, single block)
__global__ __launch_bounds__(128) void scan2(int* __restrict__ bsum) {
    __shared__ int s[98];
    int t = threadIdx.x;
    if (t < 98) s[t] = bsum[t];
    __syncthreads();
    if (t == 0) {
        int acc = 0;
        for (int i = 0; i < 98; ++i) { int v = s[i]; s[i] = acc; acc += v; }
    }
    __syncthreads();
    if (t < 98) bsum[t] = s[t];
}

// scan3: global offsets; starts[] (pristine) and cursor[] (to be mutated)
__global__ __launch_bounds__(1024) void scan3(int* __restrict__ pref,
                                              const int* __restrict__ bsum,
                                              int* __restrict__ cursor) {
    int i = blockIdx.x * 1024 + threadIdx.x;
    int v = pref[i] + bsum[blockIdx.x];
    pref[i] = v;           // pref now = global exclusive offsets ("starts")
    cursor[i] = v;
}

// ---------------------------------------------------------------------------
// Build dst-sorted edge arrays; coef computation fused.
// ---------------------------------------------------------------------------
__global__ __launch_bounds__(256) void scatter_perm(const int* __restrict__ ei,
                                                    const float* __restrict__ w,
                                                    const float* __restrict__ deg,
                                                    int* __restrict__ cursor,
                                                    int* __restrict__ srcs,
                                                    float* __restrict__ cofs) {
    int e = blockIdx.x * blockDim.x + threadIdx.x;
    if (e >= NE) return;
    int s = ei[e], d = ei[NE + e];
    float ds = deg[s], dd = deg[d];
    float is = ds > 0.f ? rsqrtf(ds) : 0.f;
    float id = dd > 0.f ? rsqrtf(dd) : 0.f;
    float cf = -(is * w[e] * id);
    int pos = atomicAdd(&cursor[d], 1);
    srcs[pos] = s;
    cofs[pos] = cf;
}

// ---------------------------------------------------------------------------
// agg_x[n] = sum coef*x[src] ; agg_h[n] = sum coef*h[src]  (no atomics)
// 32 lanes per node (one channel each), 8 nodes per 256-thread block.
// Edges loaded cooperatively 32-wide, broadcast via shfl.
// ---------------------------------------------------------------------------
__global__ __launch_bounds__(256) void agg_xh(const int* __restrict__ starts,
                                              const int* __restrict__ srcs,
                                              const float* __restrict__ cofs,
                                              const float* __restrict__ x,
                                              const float* __restrict__ h,
                                              float* __restrict__ agg_x,
                                              float* __restrict__ agg_h) {
    int tid = threadIdx.x;
    int nl = tid >> 5, j = tid & 31;
    int n = blockIdx.x * 8 + nl;
    int s0 = starts[n], s1 = starts[n + 1];
    float ax = 0.f, ah = 0.f;
    for (int base = s0; base < s1; base += 32) {
        int idx = base + j;
        int sv = 0; float cv = 0.f;
        if (idx < s1) { sv = srcs[idx]; cv = cofs[idx]; }
        int m = min(32, s1 - base);
        for (int i = 0; i < m; ++i) {
            int s = __shfl(sv, i, 32);
            float cf = __shfl(cv, i, 32);
            ax = fmaf(cf, x[(size_t)s * C + j], ax);
            ah = fmaf(cf, h[(size_t)s * C + j], ah);
        }
    }
    agg_x[(size_t)n * C + j] = ax;
    agg_h[(size_t)n * C + j] = ah;
}

// ---------------------------------------------------------------------------
// Gates z, r; hr = h*r; ph = r-independent part of h~ (x-side + biases).
// ---------------------------------------------------------------------------
__global__ __launch_bounds__(256) void gate_zr(const float* __restrict__ x,
                                               const float* __restrict__ h,
                                               const float* __restrict__ agg_x,
                                               const float* __restrict__ agg_h,
                                               const float* __restrict__ Wx,
                                               const float* __restrict__ Wh,
                                               const float* __restrict__ bx,
                                               const float* __restrict__ bh,
                                               float* __restrict__ zout,
                                               float* __restrict__ hrout,
                                               float* __restrict__ pout) {
    __shared__ float sW[10 * 1024];
    __shared__ float sIn[4][8][C];
    int tid = threadIdx.x;
    for (int i = tid; i < 10 * 1024; i += 256) {
        int m = i >> 10, r = i & 1023;
        int g = m >> 2, pair = m & 3;
        const float* src = (pair & 2) ? Wh : Wx;
        sW[i] = src[g * 2048 + (pair & 1) * 1024 + r];
    }
    int nl = tid >> 5, j = tid & 31;
    int n = blockIdx.x * 8 + nl;
    sIn[0][nl][j] = x[n * C + j];
    sIn[1][nl][j] = agg_x[n * C + j];
    sIn[2][nl][j] = h[n * C + j];
    sIn[3][nl][j] = agg_h[n * C + j];
    __syncthreads();

    float accz = bx[j] + bh[j];
    float accr = bx[32 + j] + bh[32 + j];
    float accp = bx[64 + j] + bh[64 + j];
#pragma unroll
    for (int k = 0; k < C; ++k) {
        float xk = sIn[0][nl][k];
        float ak = sIn[1][nl][k];
        float hk = sIn[2][nl][k];
        float gk = sIn[3][nl][k];
        int o = k * 32 + j;
        accz = fmaf(xk, sW[o], accz);
        accz = fmaf(ak, sW[1024 + o], accz);
        accz = fmaf(hk, sW[2048 + o], accz);
        accz = fmaf(gk, sW[3072 + o], accz);
        accr = fmaf(xk, sW[4096 + o], accr);
        accr = fmaf(ak, sW[5120 + o], accr);
        accr = fmaf(hk, sW[6144 + o], accr);
        accr = fmaf(gk, sW[7168 + o], accr);
        accp = fmaf(xk, sW[8192 + o], accp);
        accp = fmaf(ak, sW[9216 + o], accp);
    }
    float z = 1.f / (1.f + expf(-accz));
    float r = 1.f / (1.f + expf(-accr));
    zout[n * C + j]  = z;
    hrout[n * C + j] = sIn[2][nl][j] * r;
    pout[n * C + j]  = accp;
}

// ---------------------------------------------------------------------------
// Fused: agg_hr gather + h~ = tanh(ph + hr@Wh20 + agg_hr@Wh21),
// h_new = z*h + (1-z)*h~, out = softplus(relu(h_new)@Wl + bl)
// ---------------------------------------------------------------------------
__global__ __launch_bounds__(256) void final_kernel(const float* __restrict__ h,
                                                    const float* __restrict__ z,
                                                    const float* __restrict__ hr,
                                                    const float* __restrict__ ph,
                                                    const float* __restrict__ Wh,
                                                    const float* __restrict__ Wl,
                                                    const float* __restrict__ bl,
                                                    const int* __restrict__ starts,
                                                    const int* __restrict__ srcs,
                                                    const float* __restrict__ cofs,
                                                    float* __restrict__ out,
                                                    float* __restrict__ hnew) {
    __shared__ float sW[2 * 1024];
    __shared__ float sIn[2][8][C];
    int tid = threadIdx.x;
    for (int i = tid; i < 2 * 1024; i += 256) sW[i] = Wh[4096 + i]; // Wh[2,0],Wh[2,1]
    int nl = tid >> 5, j = tid & 31;
    int n = blockIdx.x * 8 + nl;

    // gather agg_hr for channel j
    int s0 = starts[n], s1 = starts[n + 1];
    float ag = 0.f;
    for (int base = s0; base < s1; base += 32) {
        int idx = base + j;
        int sv = 0; float cv = 0.f;
        if (idx < s1) { sv = srcs[idx]; cv = cofs[idx]; }
        int m = min(32, s1 - base);
        for (int i = 0; i < m; ++i) {
            int s = __shfl(sv, i, 32);
            float cf = __shfl(cv, i, 32);
            ag = fmaf(cf, hr[(size_t)s * C + j], ag);
        }
    }
    sIn[0][nl][j] = hr[n * C + j];
    sIn[1][nl][j] = ag;
    __syncthreads();

    float acc = ph[n * C + j];
#pragma unroll
    for (int k = 0; k < C; ++k) {
        int o = k * 32 + j;
        acc = fmaf(sIn[0][nl][k], sW[o], acc);
        acc = fmaf(sIn[1][nl][k], sW[1024 + o], acc);
    }
    float ht = tanhf(acc);
    float zv = z[n * C + j];
    float hv = h[n * C + j];
    float hn = fmaf(zv, hv - ht, ht);
    hnew[n * C + j] = hn;

    float p = fmaxf(hn, 0.f) * Wl[j];
#pragma unroll
    for (int off = 16; off; off >>= 1) p += __shfl_down(p, off, 32);
    if (j == 0) {
        float v = p + bl[0];
        out[n] = fmaxf(v, 0.f) + log1pf(expf(-fabsf(v)));
    }
}

// ---------------------------------------------------------------------------
extern "C" void kernel_launch(void* const* d_in, const int* in_sizes, int n_in,
                              void* d_out, int out_size, void* d_ws, size_t ws_size,
                              hipStream_t stream) {
    const float* x  = (const float*)d_in[0];
    const int*   ei = (const int*)d_in[1];
    const float* ew = (const float*)d_in[2];
    const float* h  = (const float*)d_in[3];
    const float* Wx = (const float*)d_in[4];
    const float* bx = (const float*)d_in[5];
    const float* Wh = (const float*)d_in[6];
    const float* bh = (const float*)d_in[7];
    const float* Wl = (const float*)d_in[8];
    const float* bl = (const float*)d_in[9];

    float* out  = (float*)d_out;        // [N,1]
    float* hnew = out + NN;             // [N,32]

    char* ws = (char*)d_ws;
    float* deg    = (float*)ws;                        // NP
    int*   cnt    = (int*)(deg + NP);                  // NP
    int*   pref   = (int*)(cnt + NP);                  // NP (-> starts)
    int*   cursor = (int*)(pref + NP);                 // NP
    int*   bsum   = (int*)(cursor + NP);               // 128
    int*   srcs   = (int*)(bsum + 128);                // NE
    float* cofs   = (float*)(srcs + NE);               // NE
    float* agg_x  = (float*)(cofs + NE);               // NN*C
    float* agg_h  = agg_x + (size_t)NN * C;            // NN*C
    float* zbuf   = agg_h + (size_t)NN * C;            // NN*C
    float* hrbuf  = zbuf + (size_t)NN * C;             // NN*C
    float* pbuf   = hrbuf + (size_t)NN * C;            // NN*C

    // zero deg + cnt (also covers the NP-NN padding used by the scan)
    hipMemsetAsync(d_ws, 0, (size_t)2 * NP * sizeof(float), stream);

    deg_hist    <<<(NE + 255) / 256, 256, 0, stream>>>(ei, ew, deg, cnt);
    scan1       <<<NP / 1024, 1024, 0, stream>>>(cnt, pref, bsum);
    scan2       <<<1, 128, 0, stream>>>(bsum);
    scan3       <<<NP / 1024, 1024, 0, stream>>>(pref, bsum, cursor);
    scatter_perm<<<(NE + 255) / 256, 256, 0, stream>>>(ei, ew, deg, cursor, srcs, cofs);
    agg_xh      <<<NN / 8, 256, 0, stream>>>(pref, srcs, cofs, x, h, agg_x, agg_h);
    gate_zr     <<<NN / 8, 256, 0, stream>>>(x, h, agg_x, agg_h, Wx, Wh, bx, bh,
                                             zbuf, hrbuf, pbuf);
    final_kernel<<<NN / 8, 256, 0, stream>>>(h, zbuf, hrbuf, pbuf, Wh, Wl, bl,
                                             pref, srcs, cofs, out, hnew);
}